// Round 3
// baseline (960.542 us; speedup 1.0000x reference)
//
#include <hip/hip_runtime.h>
#include <cstdint>
#include <cstddef>

// Luong attention, fp32. B=16, T=1024, S=1024, H=512
// ctx_in[b,s,h] = sum_c ctx[b,s,c] * W_a[h,c]
// scores[b,t,s] = sum_h dec[b,t,h] * ctx_in[b,s,h]; masked -> -1e6; softmax over s
// out[b,t,c]   = sum_s attn[b,t,s] * ctx[b,s,c]
//
// GEMMs: 128x128 tile, BK=16, 256 threads, 8x8/thread as 2x2 quadrants of 4x4.
// LDS intensity 2 FLOP/B matches the 128 B/cyc LDS peak at 256 FLOP/cyc VALU peak.
// Quadrant split (col = tx*4 and tx*4+64) keeps ds_read_b128 at 2-way bank
// aliasing (free, m136).
//
// ws layout (per batch-group of G): [0..255] mask flag; ctx_in G*2MB; attn G*4MB.
// G adapts to ws_size: G=16 (one pass, 4 launches) when ws >= ~96.1MB.

constexpr int BB = 16;
constexpr int TT = 1024;
constexpr int SS = 1024;
constexpr int HH = 512;

// ---------------- mask dtype detection ----------------
// int32 mask (0/1 LE): bytes at offset%4!=0 are all 0. bool/u8: ~half nonzero.
// flag=1 => byte mode, 0 => int32 mode.
__global__ __launch_bounds__(256)
void detect_mask(const unsigned char* __restrict__ mask, int* __restrict__ flag) {
    __shared__ int cnt;
    if (threadIdx.x == 0) cnt = 0;
    __syncthreads();
    int c = 0;
    for (int i = threadIdx.x; i < 4096; i += 256)
        if ((i & 3) != 0 && mask[i] != 0) c++;
    atomicAdd(&cnt, c);
    __syncthreads();
    if (threadIdx.x == 0) *flag = (cnt > 0) ? 1 : 0;
}

// ---------------- GEMM: C[M,N] = A[M,K] * B[N,K]^T ----------------
// Batched via blockIdx.z. Optional fused mask epilogue: where(mask) -> -1e6.
// maskg is the UN-offset base pointer; batch index for mask = blockIdx.z + bzOff
// (element size of mask depends on device-detected mode, so host can't offset it).
__global__ __launch_bounds__(256)
void gemm_abt(const float* __restrict__ Ag, const float* __restrict__ Bg,
              float* __restrict__ Cg,
              int M, int N, int K,
              long sA, long sB, long sC,
              const unsigned char* __restrict__ maskg, long sMask, int bzOff,
              const int* __restrict__ maskMode)
{
    const int bz = blockIdx.z;
    const float* A  = Ag + (long)bz * sA;
    const float* Bp = Bg + (long)bz * sB;

    const int tid = threadIdx.x;
    const int m0 = blockIdx.x << 7;
    const int n0 = blockIdx.y << 7;

    __shared__ __align__(16) float As[16][128];   // [k][m]
    __shared__ __align__(16) float Bs[16][128];   // [k][n]

    const int tx = tid & 15;
    const int ty = tid >> 4;

    const int lrow = tid >> 2;          // 0..63
    const int lk4  = (tid & 3) << 2;    // 0,4,8,12

    const float* Aload = A  + (long)(m0 + lrow) * K + lk4;
    const float* Bload = Bp + (long)(n0 + lrow) * K + lk4;
    const long   half  = (long)64 * K;

    float acc[2][2][4][4] = {};

    for (int k0 = 0; k0 < K; k0 += 16) {
        const float4 a0 = *(const float4*)(Aload + k0);
        const float4 a1 = *(const float4*)(Aload + half + k0);
        const float4 b0 = *(const float4*)(Bload + k0);
        const float4 b1 = *(const float4*)(Bload + half + k0);
        __syncthreads();   // previous iteration's LDS reads complete
        As[lk4 + 0][lrow]      = a0.x;
        As[lk4 + 1][lrow]      = a0.y;
        As[lk4 + 2][lrow]      = a0.z;
        As[lk4 + 3][lrow]      = a0.w;
        As[lk4 + 0][lrow + 64] = a1.x;
        As[lk4 + 1][lrow + 64] = a1.y;
        As[lk4 + 2][lrow + 64] = a1.z;
        As[lk4 + 3][lrow + 64] = a1.w;
        Bs[lk4 + 0][lrow]      = b0.x;
        Bs[lk4 + 1][lrow]      = b0.y;
        Bs[lk4 + 2][lrow]      = b0.z;
        Bs[lk4 + 3][lrow]      = b0.w;
        Bs[lk4 + 0][lrow + 64] = b1.x;
        Bs[lk4 + 1][lrow + 64] = b1.y;
        Bs[lk4 + 2][lrow + 64] = b1.z;
        Bs[lk4 + 3][lrow + 64] = b1.w;
        __syncthreads();
        #pragma unroll
        for (int k = 0; k < 16; ++k) {
            const float4 aL = *(const float4*)&As[k][ty << 2];
            const float4 aH = *(const float4*)&As[k][64 + (ty << 2)];
            const float4 bL = *(const float4*)&Bs[k][tx << 2];
            const float4 bH = *(const float4*)&Bs[k][64 + (tx << 2)];
            const float ar[2][4] = {{aL.x, aL.y, aL.z, aL.w}, {aH.x, aH.y, aH.z, aH.w}};
            const float br[2][4] = {{bL.x, bL.y, bL.z, bL.w}, {bH.x, bH.y, bH.z, bH.w}};
            #pragma unroll
            for (int qm = 0; qm < 2; ++qm)
                #pragma unroll
                for (int qn = 0; qn < 2; ++qn)
                    #pragma unroll
                    for (int i = 0; i < 4; ++i)
                        #pragma unroll
                        for (int j = 0; j < 4; ++j)
                            acc[qm][qn][i][j] = fmaf(ar[qm][i], br[qn][j], acc[qm][qn][i][j]);
        }
    }

    float* C = Cg + (long)bz * sC;
    const int mode = maskg ? *maskMode : 0;   // uniform load

    #pragma unroll
    for (int qm = 0; qm < 2; ++qm) {
        #pragma unroll
        for (int i = 0; i < 4; ++i) {
            const int r = m0 + qm * 64 + (ty << 2) + i;
            #pragma unroll
            for (int qn = 0; qn < 2; ++qn) {
                const int c = n0 + qn * 64 + (tx << 2);
                float4 v = make_float4(acc[qm][qn][i][0], acc[qm][qn][i][1],
                                       acc[qm][qn][i][2], acc[qm][qn][i][3]);
                if (maskg != nullptr) {
                    const long base = (long)(bz + bzOff) * sMask + (long)r * N + c;
                    if (mode) {  // bool / uint8 mask
                        if (maskg[base + 0]) v.x = -1000000.0f;
                        if (maskg[base + 1]) v.y = -1000000.0f;
                        if (maskg[base + 2]) v.z = -1000000.0f;
                        if (maskg[base + 3]) v.w = -1000000.0f;
                    } else {     // int32 mask
                        const int* mi = (const int*)maskg;
                        if (mi[base + 0]) v.x = -1000000.0f;
                        if (mi[base + 1]) v.y = -1000000.0f;
                        if (mi[base + 2]) v.z = -1000000.0f;
                        if (mi[base + 3]) v.w = -1000000.0f;
                    }
                }
                *(float4*)&C[(long)r * N + c] = v;
            }
        }
    }
}

// ---------------- GEMM: C[M,N] = A[M,K] * B[K,N] ----------------
__global__ __launch_bounds__(256)
void gemm_ab(const float* __restrict__ Ag, const float* __restrict__ Bg,
             float* __restrict__ Cg,
             int M, int N, int K,
             long sA, long sB, long sC)
{
    const int bz = blockIdx.z;
    const float* A  = Ag + (long)bz * sA;
    const float* Bp = Bg + (long)bz * sB;

    const int tid = threadIdx.x;
    const int m0 = blockIdx.x << 7;
    const int n0 = blockIdx.y << 7;

    __shared__ __align__(16) float As[16][128];   // [k][m]
    __shared__ __align__(16) float Bs[16][128];   // [k][n]

    const int tx = tid & 15;
    const int ty = tid >> 4;

    const int lrow = tid >> 2;          // 0..63  (A rows)
    const int lk4  = (tid & 3) << 2;    // 0,4,8,12
    const int brow = tid >> 4;          // 0..15  (B k-rows)
    const int bcol = (tid & 15) << 2;   // 0..60

    const float* Aload = A  + (long)(m0 + lrow) * K + lk4;
    const float* Bload = Bp + (long)brow * N + n0 + bcol;
    const long   half  = (long)64 * K;

    float acc[2][2][4][4] = {};

    for (int k0 = 0; k0 < K; k0 += 16) {
        const float4 a0 = *(const float4*)(Aload + k0);
        const float4 a1 = *(const float4*)(Aload + half + k0);
        const float4 b0 = *(const float4*)(Bload + (long)k0 * N);
        const float4 b1 = *(const float4*)(Bload + (long)k0 * N + 64);
        __syncthreads();
        As[lk4 + 0][lrow]      = a0.x;
        As[lk4 + 1][lrow]      = a0.y;
        As[lk4 + 2][lrow]      = a0.z;
        As[lk4 + 3][lrow]      = a0.w;
        As[lk4 + 0][lrow + 64] = a1.x;
        As[lk4 + 1][lrow + 64] = a1.y;
        As[lk4 + 2][lrow + 64] = a1.z;
        As[lk4 + 3][lrow + 64] = a1.w;
        *(float4*)&Bs[brow][bcol]      = b0;
        *(float4*)&Bs[brow][64 + bcol] = b1;
        __syncthreads();
        #pragma unroll
        for (int k = 0; k < 16; ++k) {
            const float4 aL = *(const float4*)&As[k][ty << 2];
            const float4 aH = *(const float4*)&As[k][64 + (ty << 2)];
            const float4 bL = *(const float4*)&Bs[k][tx << 2];
            const float4 bH = *(const float4*)&Bs[k][64 + (tx << 2)];
            const float ar[2][4] = {{aL.x, aL.y, aL.z, aL.w}, {aH.x, aH.y, aH.z, aH.w}};
            const float br[2][4] = {{bL.x, bL.y, bL.z, bL.w}, {bH.x, bH.y, bH.z, bH.w}};
            #pragma unroll
            for (int qm = 0; qm < 2; ++qm)
                #pragma unroll
                for (int qn = 0; qn < 2; ++qn)
                    #pragma unroll
                    for (int i = 0; i < 4; ++i)
                        #pragma unroll
                        for (int j = 0; j < 4; ++j)
                            acc[qm][qn][i][j] = fmaf(ar[qm][i], br[qn][j], acc[qm][qn][i][j]);
        }
    }

    float* C = Cg + (long)bz * sC;
    #pragma unroll
    for (int qm = 0; qm < 2; ++qm) {
        #pragma unroll
        for (int i = 0; i < 4; ++i) {
            const int r = m0 + qm * 64 + (ty << 2) + i;
            #pragma unroll
            for (int qn = 0; qn < 2; ++qn) {
                const int c = n0 + qn * 64 + (tx << 2);
                *(float4*)&C[(long)r * N + c] =
                    make_float4(acc[qm][qn][i][0], acc[qm][qn][i][1],
                                acc[qm][qn][i][2], acc[qm][qn][i][3]);
            }
        }
    }
}

// ---------------- row softmax over S=1024, one block per row ----------------
__global__ __launch_bounds__(256)
void softmax_rows(float* __restrict__ attn)
{
    __shared__ float red[8];
    const long row = blockIdx.x;
    float4* p = (float4*)(attn + row * (long)SS);
    float4 v = p[threadIdx.x];

    float m = fmaxf(fmaxf(v.x, v.y), fmaxf(v.z, v.w));
    #pragma unroll
    for (int off = 32; off; off >>= 1)
        m = fmaxf(m, __shfl_xor(m, off));
    const int wave = threadIdx.x >> 6;
    if ((threadIdx.x & 63) == 0) red[wave] = m;
    __syncthreads();
    m = fmaxf(fmaxf(red[0], red[1]), fmaxf(red[2], red[3]));

    v.x = __expf(v.x - m);
    v.y = __expf(v.y - m);
    v.z = __expf(v.z - m);
    v.w = __expf(v.w - m);

    float s = v.x + v.y + v.z + v.w;
    #pragma unroll
    for (int off = 32; off; off >>= 1)
        s += __shfl_xor(s, off);
    if ((threadIdx.x & 63) == 0) red[4 + wave] = s;
    __syncthreads();
    s = red[4] + red[5] + red[6] + red[7];

    const float inv = 1.0f / s;   // all-masked row: exps=1, s=1024 -> uniform (matches ref)
    v.x *= inv; v.y *= inv; v.z *= inv; v.w *= inv;
    p[threadIdx.x] = v;
}

// ---------------- launcher ----------------
extern "C" void kernel_launch(void* const* d_in, const int* in_sizes, int n_in,
                              void* d_out, int out_size, void* d_ws, size_t ws_size,
                              hipStream_t stream)
{
    const float*         dec  = (const float*)d_in[0];          // [B,T,H]
    const float*         ctx  = (const float*)d_in[1];          // [B,S,2H]
    const unsigned char* mask = (const unsigned char*)d_in[2];  // [B,T,S] bool or int32
    const float*         Wa   = (const float*)d_in[3];          // [H,2H]
    float* out = (float*)d_out;                                  // [B,T,2H]

    // Adaptive batch grouping: per-batch scratch = ctx_in (2MB) + attn (4MB).
    // G=16 (ws >= ~96.1MB) -> single pass, 4 GEMM/softmax launches total.
    const size_t perBatch = sizeof(float) * ((size_t)SS * HH + (size_t)TT * SS);
    const size_t avail = ws_size > 256 ? ws_size - 256 : 0;
    int G = (int)(avail / perBatch);
    if (G > BB) G = BB;
    if (G < 1)  G = 1;   // ws too small to be safe; best effort

    char* ws = (char*)d_ws;
    int*   maskMode = (int*)ws;
    float* ctxin = (float*)(ws + 256);                                      // [G,S,H]
    float* attn  = ctxin + (size_t)G * SS * HH;                             // [G,T,S]

    detect_mask<<<1, 256, 0, stream>>>(mask, maskMode);

    for (int g0 = 0; g0 < BB; g0 += G) {
        const int Gn = (BB - g0 < G) ? (BB - g0) : G;

        // K1: ctx_in[b,s,h] = sum_c ctx[b,s,c] * Wa[h,c]    (M=S, N=H, K=2H)
        gemm_abt<<<dim3(SS / 128, HH / 128, Gn), 256, 0, stream>>>(
            ctx + (size_t)g0 * SS * 2 * HH, Wa, ctxin,
            SS, HH, 2 * HH,
            (long)SS * 2 * HH, 0L, (long)SS * HH,
            nullptr, 0L, 0, nullptr);

        // K2: scores = dec . ctx_in^T, fused mask  (M=T, N=S, K=H)
        gemm_abt<<<dim3(TT / 128, SS / 128, Gn), 256, 0, stream>>>(
            dec + (size_t)g0 * TT * HH, ctxin, attn,
            TT, SS, HH,
            (long)TT * HH, (long)SS * HH, (long)TT * SS,
            mask, (long)TT * SS, g0, maskMode);

        // K3: softmax over s
        softmax_rows<<<Gn * TT, 256, 0, stream>>>(attn);

        // K4: out = attn . ctx   (M=T, N=2H, K=S)
        gemm_ab<<<dim3(TT / 128, (2 * HH) / 128, Gn), 256, 0, stream>>>(
            attn, ctx + (size_t)g0 * SS * 2 * HH, out + (size_t)g0 * TT * 2 * HH,
            TT, 2 * HH, SS,
            (long)TT * SS, (long)SS * 2 * HH, (long)TT * 2 * HH);
    }
}

// Round 5
// 678.520 us; speedup vs baseline: 1.4156x; 1.4156x over previous
//
#include <hip/hip_runtime.h>
#include <cstdint>
#include <cstddef>

// Luong attention. B=16, T=1024, S=1024, H=512
// K1: ctx_in = ctx . Wa^T     (M=S,N=H,K=2H)   bf16x3 MFMA
// K2: scores = dec . ctx_in^T (M=T,N=S,K=H)    bf16x3 MFMA
// K3: softmax(mask(scores))   row kernel, mask fused here (coalesced)
// K4: out    = attn . ctxT^T  (M=T,N=2H,K=S)   bf16x3 MFMA (ctxT from transpose pass)
//
// bf16x3: A=Ah+Al, B=Bh+Bl (RNE splits, done in-register during LDS staging);
// C = Ah.Bh + Ah.Bl + Al.Bh (Al.Bl ~2^-20 rel, dropped). Effective peak ~830 TF.
// LDS is "fragment-linear": tile[fr][lane][8 bf16] in exactly MFMA-fragment read
// order -> all ds_read_b128/ds_write_b128 are per-lane-linear, zero bank conflicts.
//
// ws per batch: ctxT 4MB + ctxin 2MB + attn 4MB = 10MB; adaptive batch-grouping.

constexpr int BB = 16;
constexpr int TT = 1024;
constexpr int SS = 1024;
constexpr int HH = 512;

typedef __attribute__((ext_vector_type(8))) short short8v;   // 8 bf16 = 4 VGPR
typedef __attribute__((ext_vector_type(4))) float f32x4;

__device__ inline unsigned short f2bf(float x) {             // RNE fp32->bf16
    unsigned int u = __float_as_uint(x);
    return (unsigned short)((u + 0x7FFFu + ((u >> 16) & 1u)) >> 16);
}
__device__ inline float bf2f(unsigned short h) {
    return __uint_as_float(((unsigned int)h) << 16);
}
__device__ inline void cvt_hl(const float4& x, const float4& y, short8v& h, short8v& l) {
    const float v[8] = {x.x, x.y, x.z, x.w, y.x, y.y, y.z, y.w};
    #pragma unroll
    for (int i = 0; i < 8; ++i) {
        const unsigned short hh = f2bf(v[i]);
        h[i] = (short)hh;
        l[i] = (short)f2bf(v[i] - bf2f(hh));
    }
}

// ---------------- mask dtype detection ----------------
// int32 mask (0/1 LE): bytes at offset%4!=0 are all 0. bool/u8: ~half nonzero.
__global__ __launch_bounds__(256)
void detect_mask(const unsigned char* __restrict__ mask, int* __restrict__ flag) {
    __shared__ int cnt;
    if (threadIdx.x == 0) cnt = 0;
    __syncthreads();
    int c = 0;
    for (int i = threadIdx.x; i < 4096; i += 256)
        if ((i & 3) != 0 && mask[i] != 0) c++;
    atomicAdd(&cnt, c);
    __syncthreads();
    if (threadIdx.x == 0) *flag = (cnt > 0) ? 1 : 0;
}

// ---------------- 1024x1024 fp32 transpose (per batch) ----------------
__global__ __launch_bounds__(256)
void transpose1024(const float* __restrict__ src, float* __restrict__ dst,
                   long sS, long sD)
{
    __shared__ float t[32][33];
    const float* s = src + (long)blockIdx.z * sS;
    float*       d = dst + (long)blockIdx.z * sD;
    const int r0 = blockIdx.x << 5;      // source row block
    const int c0 = blockIdx.y << 5;      // source col block
    const int x = threadIdx.x & 31, y = threadIdx.x >> 5;   // 32 x 8
    #pragma unroll
    for (int i = 0; i < 32; i += 8)
        t[y + i][x] = s[(long)(r0 + y + i) * 1024 + c0 + x];
    __syncthreads();
    #pragma unroll
    for (int i = 0; i < 32; i += 8)
        d[(long)(c0 + y + i) * 1024 + r0 + x] = t[x][y + i];
}

// ---------------- bf16x3 MFMA GEMM: C[M,N] = sum_k A[m,k]*B[n,k] ----------------
// 128x128 tile, BK=32, 256 threads = 4 waves (2x2), 4x4 16x16x32 fragments/wave.
// A,B fp32 row-major stride K; C fp32 row-major stride N. Batched via blockIdx.z.
__global__ __launch_bounds__(256, 2)
void gemm_bf16x3(const float* __restrict__ Ag, const float* __restrict__ Bg,
                 float* __restrict__ Cg, int N, int K,
                 long sA, long sB, long sC)
{
    const int bz = blockIdx.z;
    const float* A = Ag + (long)bz * sA;
    const float* B = Bg + (long)bz * sB;

    const int tid  = threadIdx.x;
    const int lane = tid & 63;
    const int wv   = tid >> 6;
    const int wr   = wv >> 1, wc = wv & 1;
    const int m0 = blockIdx.x << 7, n0 = blockIdx.y << 7;

    // fragment-linear LDS: [fr 0..7][lane 0..63][8 bf16]; 8 KB per array
    __shared__ short sAh[8 * 64 * 8], sAl[8 * 64 * 8];
    __shared__ short sBh[8 * 64 * 8], sBl[8 * 64 * 8];

    // staging units: u in [0,512): fr=u>>6, row=(u>>6)*16+(u&15), kk=((u>>4)&3)*8
    const int u0 = tid, u1 = tid + 256;
    const int r0u = ((u0 >> 6) << 4) + (u0 & 15), k0u = ((u0 >> 4) & 3) << 3;
    const int r1u = ((u1 >> 6) << 4) + (u1 & 15), k1u = ((u1 >> 4) & 3) << 3;

    const float* pA0 = A + (long)(m0 + r0u) * K + k0u;
    const float* pA1 = A + (long)(m0 + r1u) * K + k1u;
    const float* pB0 = B + (long)(n0 + r0u) * K + k0u;
    const float* pB1 = B + (long)(n0 + r1u) * K + k1u;

    f32x4 acc[4][4];
    #pragma unroll
    for (int i = 0; i < 4; ++i)
        #pragma unroll
        for (int j = 0; j < 4; ++j)
            acc[i][j] = (f32x4)(0.0f);

    for (int k0 = 0; k0 < K; k0 += 32) {
        const float4 a00 = *(const float4*)(pA0 + k0);
        const float4 a01 = *(const float4*)(pA0 + k0 + 4);
        const float4 a10 = *(const float4*)(pA1 + k0);
        const float4 a11 = *(const float4*)(pA1 + k0 + 4);
        const float4 b00 = *(const float4*)(pB0 + k0);
        const float4 b01 = *(const float4*)(pB0 + k0 + 4);
        const float4 b10 = *(const float4*)(pB1 + k0);
        const float4 b11 = *(const float4*)(pB1 + k0 + 4);

        short8v hA0, lA0, hA1, lA1, hB0, lB0, hB1, lB1;
        cvt_hl(a00, a01, hA0, lA0);
        cvt_hl(a10, a11, hA1, lA1);
        cvt_hl(b00, b01, hB0, lB0);
        cvt_hl(b10, b11, hB1, lB1);

        __syncthreads();   // previous iteration's fragment reads complete
        *(short8v*)&sAh[u0 * 8] = hA0;  *(short8v*)&sAl[u0 * 8] = lA0;
        *(short8v*)&sAh[u1 * 8] = hA1;  *(short8v*)&sAl[u1 * 8] = lA1;
        *(short8v*)&sBh[u0 * 8] = hB0;  *(short8v*)&sBl[u0 * 8] = lB0;
        *(short8v*)&sBh[u1 * 8] = hB1;  *(short8v*)&sBl[u1 * 8] = lB1;
        __syncthreads();

        short8v ah[4], al[4], bh[4], bl[4];
        #pragma unroll
        for (int f = 0; f < 4; ++f) {
            const int fa = (((wr << 2) + f) * 64 + lane) * 8;
            const int fb = (((wc << 2) + f) * 64 + lane) * 8;
            ah[f] = *(const short8v*)&sAh[fa];
            al[f] = *(const short8v*)&sAl[fa];
            bh[f] = *(const short8v*)&sBh[fb];
            bl[f] = *(const short8v*)&sBl[fb];
        }
        #pragma unroll
        for (int i = 0; i < 4; ++i)
            #pragma unroll
            for (int j = 0; j < 4; ++j) {
                acc[i][j] = __builtin_amdgcn_mfma_f32_16x16x32_bf16(ah[i], bh[j], acc[i][j], 0, 0, 0);
                acc[i][j] = __builtin_amdgcn_mfma_f32_16x16x32_bf16(ah[i], bl[j], acc[i][j], 0, 0, 0);
                acc[i][j] = __builtin_amdgcn_mfma_f32_16x16x32_bf16(al[i], bh[j], acc[i][j], 0, 0, 0);
            }
    }

    // C/D layout (m89-verified): col = lane&15, row = (lane>>4)*4 + reg
    float* C = Cg + (long)bz * sC;
    const int cr = (lane >> 4) << 2;
    const int cc = lane & 15;
    #pragma unroll
    for (int i = 0; i < 4; ++i) {
        const int row = m0 + (wr << 6) + (i << 4) + cr;
        #pragma unroll
        for (int j = 0; j < 4; ++j) {
            const int col = n0 + (wc << 6) + (j << 4) + cc;
            #pragma unroll
            for (int r = 0; r < 4; ++r)
                C[(long)(row + r) * N + col] = acc[i][j][r];
        }
    }
}

// ---------------- masked row softmax over S=1024, one block per row ----------------
__global__ __launch_bounds__(256)
void softmax_mask_rows(float* __restrict__ attn, const unsigned char* __restrict__ maskg,
                       const int* __restrict__ maskMode, long rowOff)
{
    __shared__ float red[8];
    const long row = blockIdx.x;
    float4* p = (float4*)(attn + row * (long)SS);
    float4 v = p[threadIdx.x];

    const long mrow = (rowOff + row) * (long)SS;
    if (*maskMode) {   // bool / uint8 mask
        const uchar4 mk = ((const uchar4*)(maskg + mrow))[threadIdx.x];
        if (mk.x) v.x = -1000000.0f;
        if (mk.y) v.y = -1000000.0f;
        if (mk.z) v.z = -1000000.0f;
        if (mk.w) v.w = -1000000.0f;
    } else {           // int32 mask
        const int4 mk = ((const int4*)((const int*)maskg + mrow))[threadIdx.x];
        if (mk.x) v.x = -1000000.0f;
        if (mk.y) v.y = -1000000.0f;
        if (mk.z) v.z = -1000000.0f;
        if (mk.w) v.w = -1000000.0f;
    }

    float m = fmaxf(fmaxf(v.x, v.y), fmaxf(v.z, v.w));
    #pragma unroll
    for (int off = 32; off; off >>= 1)
        m = fmaxf(m, __shfl_xor(m, off));
    const int wave = threadIdx.x >> 6;
    if ((threadIdx.x & 63) == 0) red[wave] = m;
    __syncthreads();
    m = fmaxf(fmaxf(red[0], red[1]), fmaxf(red[2], red[3]));

    v.x = __expf(v.x - m);
    v.y = __expf(v.y - m);
    v.z = __expf(v.z - m);
    v.w = __expf(v.w - m);

    float s = v.x + v.y + v.z + v.w;
    #pragma unroll
    for (int off = 32; off; off >>= 1)
        s += __shfl_xor(s, off);
    if ((threadIdx.x & 63) == 0) red[4 + wave] = s;
    __syncthreads();
    s = red[4] + red[5] + red[6] + red[7];

    const float inv = 1.0f / s;   // all-masked row -> uniform (matches ref)
    v.x *= inv; v.y *= inv; v.z *= inv; v.w *= inv;
    p[threadIdx.x] = v;
}

// ---------------- launcher ----------------
extern "C" void kernel_launch(void* const* d_in, const int* in_sizes, int n_in,
                              void* d_out, int out_size, void* d_ws, size_t ws_size,
                              hipStream_t stream)
{
    const float*         dec  = (const float*)d_in[0];          // [B,T,H]
    const float*         ctx  = (const float*)d_in[1];          // [B,S,2H]
    const unsigned char* mask = (const unsigned char*)d_in[2];  // [B,T,S] bool or int32
    const float*         Wa   = (const float*)d_in[3];          // [H,2H]
    float* out = (float*)d_out;                                  // [B,T,2H]

    // per-batch scratch: ctxT (2H*S) + ctxin (S*H) + attn (T*S) fp32 = 10 MB
    const size_t perBatch = sizeof(float) *
        ((size_t)2 * HH * SS + (size_t)SS * HH + (size_t)TT * SS);
    const size_t avail = ws_size > 256 ? ws_size - 256 : 0;
    int G = (int)(avail / perBatch);
    if (G > BB) G = BB;
    if (G < 1)  G = 1;

    char* ws = (char*)d_ws;
    int*   maskMode = (int*)ws;
    float* ctxT  = (float*)(ws + 256);                          // [G,2H,S]
    float* ctxin = ctxT + (size_t)G * 2 * HH * SS;              // [G,S,H]
    float* attn  = ctxin + (size_t)G * SS * HH;                 // [G,T,S]

    detect_mask<<<1, 256, 0, stream>>>(mask, maskMode);

    for (int g0 = 0; g0 < BB; g0 += G) {
        const int Gn = (BB - g0 < G) ? (BB - g0) : G;
        const float* ctxg = ctx + (size_t)g0 * SS * 2 * HH;

        // T: ctxT[b,c,s] = ctx[b,s,c]
        transpose1024<<<dim3(32, 32, Gn), 256, 0, stream>>>(
            ctxg, ctxT, (long)SS * 2 * HH, (long)2 * HH * SS);

        // K1: ctx_in = ctx . Wa^T   (M=S, N=H, K=2H)
        gemm_bf16x3<<<dim3(SS / 128, HH / 128, Gn), 256, 0, stream>>>(
            ctxg, Wa, ctxin, HH, 2 * HH,
            (long)SS * 2 * HH, 0L, (long)SS * HH);

        // K2: scores = dec . ctx_in^T   (M=T, N=S, K=H)
        gemm_bf16x3<<<dim3(TT / 128, SS / 128, Gn), 256, 0, stream>>>(
            dec + (size_t)g0 * TT * HH, ctxin, attn, SS, HH,
            (long)TT * HH, (long)SS * HH, (long)TT * SS);

        // K3: masked softmax over s
        softmax_mask_rows<<<Gn * TT, 256, 0, stream>>>(
            attn, mask, maskMode, (long)g0 * TT);

        // K4: out = attn . ctxT^T   (M=T, N=2H, K=S)
        gemm_bf16x3<<<dim3(TT / 128, (2 * HH) / 128, Gn), 256, 0, stream>>>(
            attn, ctxT, out + (size_t)g0 * TT * 2 * HH, 2 * HH, SS,
            (long)TT * SS, (long)2 * HH * SS, (long)TT * 2 * HH);
    }
}

// Round 6
// 456.014 us; speedup vs baseline: 2.1064x; 1.4879x over previous
//
#include <hip/hip_runtime.h>
#include <cstdint>
#include <cstddef>

// Luong attention. B=16, T=1024, S=1024, H=512
// Pre-split fp32 -> bf16 hi/lo passes, then pure-bf16 MFMA GEMMs:
//  K1: ctxin(hi,lo) = ctx . Wa^T      bf16x3 (3 MFMA/frag-pair), split epilogue
//  K2: scores(f32)  = dec . ctxin^T   bf16x3
//  K3: softmax(mask(scores)) -> attn bf16 (fused mask + bf16 epilogue)
//  K4: out(f32)     = attn . ctxT^T   plain bf16 (attn in [0,1]; err ~1e-4)
// GEMM staging: global_load_lds(16B) direct into fragment-linear LDS
// ([frag][lane][8 bf16] = MFMA read order; linear in lane order => gload-compatible,
// zero bank conflicts — both verified in round 5).
//
// ws: 256B flag | WaH/WaL 2MB | per-G: P(4MB: ctxH+ctxL, reused as attnF)
//   Q(2MB: ctxinH+ctxinL, reused as attnB) | decH/decL 2MB | ctxT 2MB  = 10MB/batch.

constexpr int BB = 16;
constexpr int TT = 1024;
constexpr int SS = 1024;
constexpr int HH = 512;

typedef __attribute__((ext_vector_type(8))) short short8v;   // 8 bf16 = 4 VGPR
typedef __attribute__((ext_vector_type(4))) float f32x4;

__device__ inline unsigned short f2bf(float x) {             // RNE fp32->bf16
    unsigned int u = __float_as_uint(x);
    return (unsigned short)((u + 0x7FFFu + ((u >> 16) & 1u)) >> 16);
}
__device__ inline float bf2f(unsigned short h) {
    return __uint_as_float(((unsigned int)h) << 16);
}

__device__ inline void gload16(const void* g, void* l) {
    __builtin_amdgcn_global_load_lds(
        (const __attribute__((address_space(1))) unsigned int*)g,
        (__attribute__((address_space(3))) unsigned int*)l, 16, 0, 0);
}

// ---------------- mask dtype detection (flag=1 byte-mask, 0 int32-mask) --------
__global__ __launch_bounds__(256)
void detect_mask(const unsigned char* __restrict__ mask, int* __restrict__ flag) {
    __shared__ int cnt;
    if (threadIdx.x == 0) cnt = 0;
    __syncthreads();
    int c = 0;
    for (int i = threadIdx.x; i < 4096; i += 256)
        if ((i & 3) != 0 && mask[i] != 0) c++;
    atomicAdd(&cnt, c);
    __syncthreads();
    if (threadIdx.x == 0) *flag = (cnt > 0) ? 1 : 0;
}

// ---------------- fp32 -> bf16 hi/lo split, 8 elems/thread ----------------
__global__ __launch_bounds__(256)
void split_hl(const float* __restrict__ in, unsigned short* __restrict__ oh,
              unsigned short* __restrict__ ol)
{
    const size_t i = ((size_t)blockIdx.x * 256 + threadIdx.x) * 8;
    const float4 x = *(const float4*)(in + i);
    const float4 y = *(const float4*)(in + i + 4);
    const float v[8] = {x.x, x.y, x.z, x.w, y.x, y.y, y.z, y.w};
    short8v H, L;
    #pragma unroll
    for (int j = 0; j < 8; ++j) {
        const unsigned short h = f2bf(v[j]);
        H[j] = (short)h;
        L[j] = (short)f2bf(v[j] - bf2f(h));
    }
    *(short8v*)(oh + i) = H;
    *(short8v*)(ol + i) = L;
}

// ---------------- 1024x1024 fp32 -> bf16 transpose (per batch) ----------------
__global__ __launch_bounds__(256)
void transpose_bf16(const float* __restrict__ src, unsigned short* __restrict__ dst,
                    long sS, long sD)
{
    __shared__ float t[32][33];
    const float*    s = src + (long)blockIdx.z * sS;
    unsigned short* d = dst + (long)blockIdx.z * sD;
    const int r0 = blockIdx.x << 5, c0 = blockIdx.y << 5;
    const int x = threadIdx.x & 31, y = threadIdx.x >> 5;
    #pragma unroll
    for (int i = 0; i < 32; i += 8)
        t[y + i][x] = s[(long)(r0 + y + i) * 1024 + c0 + x];
    __syncthreads();
    #pragma unroll
    for (int i = 0; i < 32; i += 8)
        d[(long)(c0 + y + i) * 1024 + r0 + x] = f2bf(t[x][y + i]);
}

// ---------------- bf16x3 GEMM: C[M,N] = sum_k (Ah+Al)[m,k]*(Bh+Bl)[n,k] --------
// 128x128 tile, BK=32, 4 waves (2x2), 4x4 16x16x32 frags/wave, 48 MFMA/K-step.
// SPLIT: write C as bf16 hi/lo pair (for K1 -> ctxin); else fp32.
template <bool SPLIT>
__global__ __launch_bounds__(256, 2)
void gemm_x3(const unsigned short* __restrict__ Ah, const unsigned short* __restrict__ Al,
             const unsigned short* __restrict__ Bh, const unsigned short* __restrict__ Bl,
             float* __restrict__ C, unsigned short* __restrict__ CH,
             unsigned short* __restrict__ CL,
             int N, int K, long sA, long sB, long sC)
{
    const int bz = blockIdx.z;
    Ah += (size_t)bz * sA;  Al += (size_t)bz * sA;
    Bh += (size_t)bz * sB;  Bl += (size_t)bz * sB;

    const int tid = threadIdx.x, lane = tid & 63, wv = tid >> 6;
    const int wr = wv >> 1, wc = wv & 1;
    const int m0 = blockIdx.x << 7, n0 = blockIdx.y << 7;

    __shared__ short sAh[8 * 512], sAl[8 * 512], sBh[8 * 512], sBl[8 * 512];

    // per-wave staging: wave wv stages one array, 8 fragments of 1KB each.
    // fragment f: lane l <- global[r0 + f*16 + (l&15)][k0 + (l>>4)*8 .. +7]
    const int r15 = lane & 15, k8 = (lane >> 4) << 3;
    const unsigned short* g;
    short* lw;
    if (wv == 0)      { g = Ah + (size_t)(m0 + r15) * K + k8; lw = sAh; }
    else if (wv == 1) { g = Al + (size_t)(m0 + r15) * K + k8; lw = sAl; }
    else if (wv == 2) { g = Bh + (size_t)(n0 + r15) * K + k8; lw = sBh; }
    else              { g = Bl + (size_t)(n0 + r15) * K + k8; lw = sBl; }

    f32x4 acc[4][4];
    #pragma unroll
    for (int i = 0; i < 4; ++i)
        #pragma unroll
        for (int j = 0; j < 4; ++j)
            acc[i][j] = (f32x4)(0.0f);

    for (int k0 = 0; k0 < K; k0 += 32) {
        __syncthreads();                      // prev tile's reads complete
        #pragma unroll
        for (int f = 0; f < 8; ++f)
            gload16(g + (size_t)f * 16 * K + k0, lw + f * 512);
        __syncthreads();                      // staged (vmcnt drain + barrier)

        short8v ah[4], al[4], bh[4], bl[4];
        #pragma unroll
        for (int f = 0; f < 4; ++f) {
            const int fa = (((wr << 2) + f) * 64 + lane) * 8;
            const int fb = (((wc << 2) + f) * 64 + lane) * 8;
            ah[f] = *(const short8v*)&sAh[fa];
            al[f] = *(const short8v*)&sAl[fa];
            bh[f] = *(const short8v*)&sBh[fb];
            bl[f] = *(const short8v*)&sBl[fb];
        }
        #pragma unroll
        for (int i = 0; i < 4; ++i)
            #pragma unroll
            for (int j = 0; j < 4; ++j) {
                acc[i][j] = __builtin_amdgcn_mfma_f32_16x16x32_bf16(ah[i], bh[j], acc[i][j], 0, 0, 0);
                acc[i][j] = __builtin_amdgcn_mfma_f32_16x16x32_bf16(ah[i], bl[j], acc[i][j], 0, 0, 0);
                acc[i][j] = __builtin_amdgcn_mfma_f32_16x16x32_bf16(al[i], bh[j], acc[i][j], 0, 0, 0);
            }
    }

    // C/D: col = lane&15, row = (lane>>4)*4 + reg  (HW-verified round 5)
    const int cr = (lane >> 4) << 2, cc = lane & 15;
    #pragma unroll
    for (int i = 0; i < 4; ++i) {
        const int row = m0 + (wr << 6) + (i << 4) + cr;
        #pragma unroll
        for (int j = 0; j < 4; ++j) {
            const int col = n0 + (wc << 6) + (j << 4) + cc;
            #pragma unroll
            for (int r = 0; r < 4; ++r) {
                const size_t idx = (size_t)bz * sC + (size_t)(row + r) * N + col;
                const float v = acc[i][j][r];
                if (SPLIT) {
                    const unsigned short h = f2bf(v);
                    CH[idx] = h;
                    CL[idx] = f2bf(v - bf2f(h));
                } else {
                    C[idx] = v;
                }
            }
        }
    }
}

// ---------------- plain-bf16 GEMM: C[M,N] = sum_k A[m,k]*B[n,k] ----------------
__global__ __launch_bounds__(256, 2)
void gemm_x1(const unsigned short* __restrict__ A, const unsigned short* __restrict__ B,
             float* __restrict__ C, int N, int K, long sA, long sB, long sC)
{
    const int bz = blockIdx.z;
    A += (size_t)bz * sA;
    B += (size_t)bz * sB;

    const int tid = threadIdx.x, lane = tid & 63, wv = tid >> 6;
    const int wr = wv >> 1, wc = wv & 1;
    const int m0 = blockIdx.x << 7, n0 = blockIdx.y << 7;

    __shared__ short sA_[8 * 512], sB_[8 * 512];

    // waves 0,1 stage A fragments [half*4, half*4+4); waves 2,3 stage B.
    const int r15 = lane & 15, k8 = (lane >> 4) << 3;
    const int half = wv & 1;
    const unsigned short* g;
    short* lw;
    if (wv < 2) { g = A + (size_t)(m0 + (half << 6) + r15) * K + k8; lw = sA_ + (half << 2) * 512; }
    else        { g = B + (size_t)(n0 + (half << 6) + r15) * K + k8; lw = sB_ + (half << 2) * 512; }

    f32x4 acc[4][4];
    #pragma unroll
    for (int i = 0; i < 4; ++i)
        #pragma unroll
        for (int j = 0; j < 4; ++j)
            acc[i][j] = (f32x4)(0.0f);

    for (int k0 = 0; k0 < K; k0 += 32) {
        __syncthreads();
        #pragma unroll
        for (int f = 0; f < 4; ++f)
            gload16(g + (size_t)f * 16 * K + k0, lw + f * 512);
        __syncthreads();

        short8v a[4], b[4];
        #pragma unroll
        for (int f = 0; f < 4; ++f) {
            a[f] = *(const short8v*)&sA_[(((wr << 2) + f) * 64 + lane) * 8];
            b[f] = *(const short8v*)&sB_[(((wc << 2) + f) * 64 + lane) * 8];
        }
        #pragma unroll
        for (int i = 0; i < 4; ++i)
            #pragma unroll
            for (int j = 0; j < 4; ++j)
                acc[i][j] = __builtin_amdgcn_mfma_f32_16x16x32_bf16(a[i], b[j], acc[i][j], 0, 0, 0);
    }

    float* Cb = C + (size_t)bz * sC;
    const int cr = (lane >> 4) << 2, cc = lane & 15;
    #pragma unroll
    for (int i = 0; i < 4; ++i) {
        const int row = m0 + (wr << 6) + (i << 4) + cr;
        #pragma unroll
        for (int j = 0; j < 4; ++j) {
            const int col = n0 + (wc << 6) + (j << 4) + cc;
            #pragma unroll
            for (int r = 0; r < 4; ++r)
                Cb[(size_t)(row + r) * N + col] = acc[i][j][r];
        }
    }
}

// ------------- masked row softmax, fp32 in -> bf16 out, 1 block/row -------------
__global__ __launch_bounds__(256)
void softmax_mask_bf16(const float* __restrict__ attnF, unsigned short* __restrict__ attnB,
                       const unsigned char* __restrict__ maskg,
                       const int* __restrict__ maskMode, long rowOff)
{
    __shared__ float red[8];
    const long row = blockIdx.x;
    const float4* p = (const float4*)(attnF + row * (long)SS);
    float4 v = p[threadIdx.x];

    const long mrow = (rowOff + row) * (long)SS;
    if (*maskMode) {   // byte mask
        const uchar4 mk = ((const uchar4*)(maskg + mrow))[threadIdx.x];
        if (mk.x) v.x = -1000000.0f;
        if (mk.y) v.y = -1000000.0f;
        if (mk.z) v.z = -1000000.0f;
        if (mk.w) v.w = -1000000.0f;
    } else {           // int32 mask
        const int4 mk = ((const int4*)((const int*)maskg + mrow))[threadIdx.x];
        if (mk.x) v.x = -1000000.0f;
        if (mk.y) v.y = -1000000.0f;
        if (mk.z) v.z = -1000000.0f;
        if (mk.w) v.w = -1000000.0f;
    }

    float m = fmaxf(fmaxf(v.x, v.y), fmaxf(v.z, v.w));
    #pragma unroll
    for (int off = 32; off; off >>= 1)
        m = fmaxf(m, __shfl_xor(m, off));
    const int wave = threadIdx.x >> 6;
    if ((threadIdx.x & 63) == 0) red[wave] = m;
    __syncthreads();
    m = fmaxf(fmaxf(red[0], red[1]), fmaxf(red[2], red[3]));

    v.x = __expf(v.x - m);
    v.y = __expf(v.y - m);
    v.z = __expf(v.z - m);
    v.w = __expf(v.w - m);

    float s = v.x + v.y + v.z + v.w;
    #pragma unroll
    for (int off = 32; off; off >>= 1)
        s += __shfl_xor(s, off);
    if ((threadIdx.x & 63) == 0) red[4 + wave] = s;
    __syncthreads();
    s = red[4] + red[5] + red[6] + red[7];

    const float inv = 1.0f / s;   // all-masked row -> uniform (matches ref)
    ushort4 o;
    o.x = f2bf(v.x * inv);
    o.y = f2bf(v.y * inv);
    o.z = f2bf(v.z * inv);
    o.w = f2bf(v.w * inv);
    *(ushort4*)(attnB + row * (long)SS + 4 * threadIdx.x) = o;
}

// ---------------- launcher ----------------
extern "C" void kernel_launch(void* const* d_in, const int* in_sizes, int n_in,
                              void* d_out, int out_size, void* d_ws, size_t ws_size,
                              hipStream_t stream)
{
    const float*         dec  = (const float*)d_in[0];          // [B,T,H]
    const float*         ctx  = (const float*)d_in[1];          // [B,S,2H]
    const unsigned char* mask = (const unsigned char*)d_in[2];  // [B,T,S]
    const float*         Wa   = (const float*)d_in[3];          // [H,2H]
    float* out = (float*)d_out;                                  // [B,T,2H]

    const size_t MBy = 1u << 20;
    const size_t perBatch = 10 * MBy;               // P4 + Q2 + dec2 + ctxT2
    const size_t fixed = 256 + 2 * MBy;             // flag + WaH/WaL
    int G = (ws_size > fixed) ? (int)((ws_size - fixed) / perBatch) : 1;
    if (G > BB) G = BB;
    if (G < 1)  G = 1;

    char* p = (char*)d_ws;
    int* maskMode = (int*)p;                 p += 256;
    unsigned short* WaH = (unsigned short*)p; p += (size_t)HH * 2 * HH * 2;   // 1MB
    unsigned short* WaL = (unsigned short*)p; p += (size_t)HH * 2 * HH * 2;   // 1MB
    // P region: ctxH+ctxL during split->K1, reused as attnF (f32) during K2->softmax
    unsigned short* ctxH = (unsigned short*)p;
    unsigned short* ctxL = ctxH + (size_t)G * SS * 2 * HH;
    float*          attnF = (float*)p;       p += (size_t)G * SS * 2 * HH * 4;  // 4MB*G
    // Q region: ctxinH+ctxinL during K1->K2, reused as attnB during softmax->K4
    unsigned short* cinH = (unsigned short*)p;
    unsigned short* cinL = cinH + (size_t)G * SS * HH;
    unsigned short* attnB = (unsigned short*)p;  p += (size_t)G * SS * HH * 2 * 2; // 2MB*G
    unsigned short* decH = (unsigned short*)p;   p += (size_t)G * TT * HH * 2;     // 1MB*G
    unsigned short* decL = (unsigned short*)p;   p += (size_t)G * TT * HH * 2;     // 1MB*G
    unsigned short* ctxT = (unsigned short*)p;   p += (size_t)G * 2 * HH * SS * 2; // 2MB*G

    detect_mask<<<1, 256, 0, stream>>>(mask, maskMode);
    split_hl<<<(HH * 2 * HH) / 2048, 256, 0, stream>>>(Wa, WaH, WaL);

    for (int g0 = 0; g0 < BB; g0 += G) {
        const int Gn = (BB - g0 < G) ? (BB - g0) : G;
        const float* ctxg = ctx + (size_t)g0 * SS * 2 * HH;

        split_hl<<<(Gn * SS * 2 * HH) / 2048, 256, 0, stream>>>(ctxg, ctxH, ctxL);
        split_hl<<<(Gn * TT * HH) / 2048, 256, 0, stream>>>(
            dec + (size_t)g0 * TT * HH, decH, decL);
        transpose_bf16<<<dim3(32, 32, Gn), 256, 0, stream>>>(
            ctxg, ctxT, (long)SS * 2 * HH, (long)2 * HH * SS);

        // K1: ctxin(h,l) = ctx . Wa^T   (M=S, N=H, K=2H), split epilogue
        gemm_x3<true><<<dim3(SS / 128, HH / 128, Gn), 256, 0, stream>>>(
            ctxH, ctxL, WaH, WaL, nullptr, cinH, cinL,
            HH, 2 * HH, (long)SS * 2 * HH, 0L, (long)SS * HH);

        // K2: scores = dec . ctxin^T   (M=T, N=S, K=H), fp32 out (overwrites ctxH/L)
        gemm_x3<false><<<dim3(TT / 128, SS / 128, Gn), 256, 0, stream>>>(
            decH, decL, cinH, cinL, attnF, nullptr, nullptr,
            SS, HH, (long)TT * HH, (long)SS * HH, (long)TT * SS);

        // K3: masked softmax -> bf16 attn (overwrites ctxinH/L)
        softmax_mask_bf16<<<Gn * TT, 256, 0, stream>>>(
            attnF, attnB, mask, maskMode, (long)g0 * TT);

        // K4: out = attn . ctxT^T   (M=T, N=2H, K=S), plain bf16
        gemm_x1<<<dim3(TT / 128, (2 * HH) / 128, Gn), 256, 0, stream>>>(
            attnB, ctxT, out + (size_t)g0 * TT * 2 * HH,
            2 * HH, SS, (long)TT * SS, (long)2 * HH * SS, (long)TT * 2 * HH);
    }
}

// Round 8
// 433.873 us; speedup vs baseline: 2.2139x; 1.0510x over previous
//
#include <hip/hip_runtime.h>
#include <cstdint>
#include <cstddef>

// Luong attention. B=16, T=1024, S=1024, H=512
// All GEMM operands pre-PACKED into MFMA-fragment order:
//   operand [R x K] -> tiles (rt, kt) of 128x32, each an 8KB block of
//   4096 bf16: idx = (frag*64 + lane)*8 + e  <->  r = frag*16 + (lane&15),
//   k = (lane>>4)*8 + e.   Staging = contiguous 1KB/wave global_load_lds.
// GEMM K-loop: 2-phase double-buffered prefetch (STAGE(next) issued before
// compute(cur), ONE barrier per K-step) per T3-minimum recipe.
//  K1: cin(h,l) = ctx . Wa^T    bf16x3, split epilogue (linear out, packed later)
//  K2: attnF    = dec . cin^T   bf16x3
//  K3: masked softmax -> attnB bf16 linear; pack -> attnP
//  K4: out      = attn . ctxT^T bf16x1
// ws regions per batch (12MB): A(4): ctxHP+LP / attnF | B(2): decHP+LP / attnB
//   C(2): cin linear / attnP | D(2): cin packed | E(2): ctxTP.  +2MB WaP fixed.

constexpr int BB = 16;
constexpr int TT = 1024;
constexpr int SS = 1024;
constexpr int HH = 512;

typedef __attribute__((ext_vector_type(8))) short short8v;
typedef __attribute__((ext_vector_type(4))) float f32x4;

__device__ inline unsigned short f2bf(float x) {             // RNE fp32->bf16
    unsigned int u = __float_as_uint(x);
    return (unsigned short)((u + 0x7FFFu + ((u >> 16) & 1u)) >> 16);
}
__device__ inline float bf2f(unsigned short h) {
    return __uint_as_float(((unsigned int)h) << 16);
}
__device__ inline void gload16(const void* g, void* l) {
    __builtin_amdgcn_global_load_lds(
        (const __attribute__((address_space(1))) unsigned int*)g,
        (__attribute__((address_space(3))) unsigned int*)l, 16, 0, 0);
}

// ---------------- mask dtype detection (flag=1 byte-mask, 0 int32-mask) --------
__global__ __launch_bounds__(256)
void detect_mask(const unsigned char* __restrict__ mask, int* __restrict__ flag) {
    __shared__ int cnt;
    if (threadIdx.x == 0) cnt = 0;
    __syncthreads();
    int c = 0;
    for (int i = threadIdx.x; i < 4096; i += 256)
        if ((i & 3) != 0 && mask[i] != 0) c++;
    atomicAdd(&cnt, c);
    __syncthreads();
    if (threadIdx.x == 0) *flag = (cnt > 0) ? 1 : 0;
}

// -------- fp32 [R x K] -> packed bf16 hi & lo. grid.x = (R/128)*(K/32) --------
__global__ __launch_bounds__(256)
void split_pack(const float* __restrict__ in, unsigned short* __restrict__ oh,
                unsigned short* __restrict__ ol, int K, int KT, long sIn, long sOut)
{
    in += (size_t)blockIdx.z * sIn;
    oh += (size_t)blockIdx.z * sOut;
    ol += (size_t)blockIdx.z * sOut;
    const int rt = blockIdx.x / KT, kt = blockIdx.x % KT;
    const size_t tileBase = (size_t)blockIdx.x * 4096;
    #pragma unroll
    for (int s = 0; s < 2; ++s) {
        const int u  = threadIdx.x + (s << 8);
        const int r  = ((u >> 6) << 4) + (u & 15);
        const int k8 = ((u >> 4) & 3) << 3;
        const float* src = in + (size_t)(rt * 128 + r) * K + kt * 32 + k8;
        const float4 x = *(const float4*)src;
        const float4 y = *(const float4*)(src + 4);
        const float v[8] = {x.x, x.y, x.z, x.w, y.x, y.y, y.z, y.w};
        short8v H, L;
        #pragma unroll
        for (int j = 0; j < 8; ++j) {
            const unsigned short h = f2bf(v[j]);
            H[j] = (short)h;
            L[j] = (short)f2bf(v[j] - bf2f(h));
        }
        *(short8v*)(oh + tileBase + (size_t)u * 8) = H;
        *(short8v*)(ol + tileBase + (size_t)u * 8) = L;
    }
}

// -------- bf16 linear [R x K] -> packed. grid.x = (R/128)*(K/32) --------
__global__ __launch_bounds__(256)
void pack_bf16(const unsigned short* __restrict__ in, unsigned short* __restrict__ op,
               int K, int KT, long sIn, long sOut)
{
    in += (size_t)blockIdx.z * sIn;
    op += (size_t)blockIdx.z * sOut;
    const int rt = blockIdx.x / KT, kt = blockIdx.x % KT;
    const size_t tileBase = (size_t)blockIdx.x * 4096;
    #pragma unroll
    for (int s = 0; s < 2; ++s) {
        const int u  = threadIdx.x + (s << 8);
        const int r  = ((u >> 6) << 4) + (u & 15);
        const int k8 = ((u >> 4) & 3) << 3;
        const short8v v = *(const short8v*)(in + (size_t)(rt * 128 + r) * K + kt * 32 + k8);
        *(short8v*)(op + tileBase + (size_t)u * 8) = v;
    }
}

// -------- ctx [S x 2H] fp32 -> ctxT packed (rows=c, k=s), hi only --------
// grid (ct = 2H/128, st = S/32, batch)
__global__ __launch_bounds__(256)
void transpose_pack(const float* __restrict__ src, unsigned short* __restrict__ dst,
                    long sIn, long sOut)
{
    __shared__ float t[32][132];
    src += (size_t)blockIdx.z * sIn;
    dst += (size_t)blockIdx.z * sOut;
    const int c0 = blockIdx.x << 7, s0 = blockIdx.y << 5;
    #pragma unroll
    for (int i = 0; i < 4; ++i) {
        const int fl = threadIdx.x + (i << 8);       // float4 id in 32x128 tile
        const int srow = fl >> 5, c4 = fl & 31;
        const float4 v = *(const float4*)(src + (size_t)(s0 + srow) * (2 * HH) + c0 + (c4 << 2));
        t[srow][(c4 << 2) + 0] = v.x;
        t[srow][(c4 << 2) + 1] = v.y;
        t[srow][(c4 << 2) + 2] = v.z;
        t[srow][(c4 << 2) + 3] = v.w;
    }
    __syncthreads();
    const size_t tileBase = ((size_t)blockIdx.x * (SS / 32) + blockIdx.y) * 4096;
    #pragma unroll
    for (int s = 0; s < 2; ++s) {
        const int u = threadIdx.x + (s << 8);
        const int r = ((u >> 6) << 4) + (u & 15);    // c-row within tile
        const int o = (u >> 4) & 3;                  // s-octet
        short8v H;
        #pragma unroll
        for (int e = 0; e < 8; ++e)
            H[e] = (short)f2bf(t[(o << 3) + e][r]);
        *(short8v*)(dst + tileBase + (size_t)u * 8) = H;
    }
}

// -------- bf16x3 GEMM on packed operands, 2-phase prefetch --------
// C[M,N] = sum (Ah+Al)[m,k]*(Bh+Bl)[n,k]; 128x128 tile, BK=32, 4 waves.
template <bool SPLIT>
__global__ __launch_bounds__(256, 2)
void gemm2_x3(const unsigned short* __restrict__ Ah, const unsigned short* __restrict__ Al,
              const unsigned short* __restrict__ Bh, const unsigned short* __restrict__ Bl,
              float* __restrict__ C, unsigned short* __restrict__ CH,
              unsigned short* __restrict__ CL,
              int N, int KTn, long sA, long sB, long sC)
{
    const int bz = blockIdx.z;
    const int tid = threadIdx.x, lane = tid & 63, wv = tid >> 6;
    const int wr = wv >> 1, wc = wv & 1;
    const int bx = blockIdx.x, by = blockIdx.y;

    __shared__ short sm[2][4][4096];    // [buf][Ah,Al,Bh,Bl][frag*512+lane*8]

    const unsigned short* base =
        (wv == 0) ? Ah + (size_t)bz * sA : (wv == 1) ? Al + (size_t)bz * sA
      : (wv == 2) ? Bh + (size_t)bz * sB :            Bl + (size_t)bz * sB;
    const unsigned short* gsrc = base
        + (size_t)((wv < 2) ? bx : by) * KTn * 4096 + (size_t)lane * 8;

    f32x4 acc[4][4];
    #pragma unroll
    for (int i = 0; i < 4; ++i)
        #pragma unroll
        for (int j = 0; j < 4; ++j)
            acc[i][j] = (f32x4)(0.0f);

    // prologue: stage tile 0 into buf 0
    #pragma unroll
    for (int f = 0; f < 8; ++f)
        gload16(gsrc + f * 512, &sm[0][wv][f * 512]);
    __syncthreads();

    int cur = 0;
    for (int kt = 0; kt < KTn; ++kt) {
        if (kt + 1 < KTn) {              // issue next tile's loads FIRST
            const unsigned short* g = gsrc + (size_t)(kt + 1) * 4096;
            #pragma unroll
            for (int f = 0; f < 8; ++f)
                gload16(g + f * 512, &sm[cur ^ 1][wv][f * 512]);
        }
        short8v ah[4], al[4], bh[4], bl[4];
        #pragma unroll
        for (int f = 0; f < 4; ++f) {
            const int fa = (((wr << 2) + f) * 64 + lane) * 8;
            const int fb = (((wc << 2) + f) * 64 + lane) * 8;
            ah[f] = *(const short8v*)&sm[cur][0][fa];
            al[f] = *(const short8v*)&sm[cur][1][fa];
            bh[f] = *(const short8v*)&sm[cur][2][fb];
            bl[f] = *(const short8v*)&sm[cur][3][fb];
        }
        #pragma unroll
        for (int i = 0; i < 4; ++i)
            #pragma unroll
            for (int j = 0; j < 4; ++j) {
                acc[i][j] = __builtin_amdgcn_mfma_f32_16x16x32_bf16(ah[i], bh[j], acc[i][j], 0, 0, 0);
                acc[i][j] = __builtin_amdgcn_mfma_f32_16x16x32_bf16(ah[i], bl[j], acc[i][j], 0, 0, 0);
                acc[i][j] = __builtin_amdgcn_mfma_f32_16x16x32_bf16(al[i], bh[j], acc[i][j], 0, 0, 0);
            }
        __syncthreads();                 // drain loads (vmcnt0) + flip
        cur ^= 1;
    }

    // C/D: col = lane&15, row = (lane>>4)*4 + reg  (HW-verified)
    const int cr = (lane >> 4) << 2, cc = lane & 15;
    #pragma unroll
    for (int i = 0; i < 4; ++i) {
        const int row = (bx << 7) + (wr << 6) + (i << 4) + cr;
        #pragma unroll
        for (int j = 0; j < 4; ++j) {
            const int col = (by << 7) + (wc << 6) + (j << 4) + cc;
            #pragma unroll
            for (int r = 0; r < 4; ++r) {
                const size_t idx = (size_t)bz * sC + (size_t)(row + r) * N + col;
                const float v = acc[i][j][r];
                if (SPLIT) {
                    const unsigned short h = f2bf(v);
                    CH[idx] = h;
                    CL[idx] = f2bf(v - bf2f(h));
                } else {
                    C[idx] = v;
                }
            }
        }
    }
}

// -------- bf16x1 GEMM on packed operands, 2-phase prefetch --------
__global__ __launch_bounds__(256, 2)
void gemm2_x1(const unsigned short* __restrict__ A, const unsigned short* __restrict__ B,
              float* __restrict__ C, int N, int KTn, long sA, long sB, long sC)
{
    const int bz = blockIdx.z;
    const int tid = threadIdx.x, lane = tid & 63, wv = tid >> 6;
    const int wr = wv >> 1, wc = wv & 1;
    const int bx = blockIdx.x, by = blockIdx.y;

    __shared__ short sm[2][2][4096];    // [buf][A,B][...]

    const int half = wv & 1;
    const unsigned short* base = (wv < 2) ? A + (size_t)bz * sA : B + (size_t)bz * sB;
    const unsigned short* gsrc = base
        + (size_t)((wv < 2) ? bx : by) * KTn * 4096 + (size_t)(half * 4) * 512
        + (size_t)lane * 8;
    short* ldst = &sm[0][wv < 2 ? 0 : 1][half * 2048];

    f32x4 acc[4][4];
    #pragma unroll
    for (int i = 0; i < 4; ++i)
        #pragma unroll
        for (int j = 0; j < 4; ++j)
            acc[i][j] = (f32x4)(0.0f);

    #pragma unroll
    for (int f = 0; f < 4; ++f)
        gload16(gsrc + f * 512, ldst + f * 512);
    __syncthreads();

    int cur = 0;
    for (int kt = 0; kt < KTn; ++kt) {
        if (kt + 1 < KTn) {
            const unsigned short* g = gsrc + (size_t)(kt + 1) * 4096;
            short* l = &sm[cur ^ 1][wv < 2 ? 0 : 1][half * 2048];
            #pragma unroll
            for (int f = 0; f < 4; ++f)
                gload16(g + f * 512, l + f * 512);
        }
        short8v a[4], b[4];
        #pragma unroll
        for (int f = 0; f < 4; ++f) {
            a[f] = *(const short8v*)&sm[cur][0][(((wr << 2) + f) * 64 + lane) * 8];
            b[f] = *(const short8v*)&sm[cur][1][(((wc << 2) + f) * 64 + lane) * 8];
        }
        #pragma unroll
        for (int i = 0; i < 4; ++i)
            #pragma unroll
            for (int j = 0; j < 4; ++j)
                acc[i][j] = __builtin_amdgcn_mfma_f32_16x16x32_bf16(a[i], b[j], acc[i][j], 0, 0, 0);
        __syncthreads();
        cur ^= 1;
    }

    float* Cb = C + (size_t)bz * sC;
    const int cr = (lane >> 4) << 2, cc = lane & 15;
    #pragma unroll
    for (int i = 0; i < 4; ++i) {
        const int row = (bx << 7) + (wr << 6) + (i << 4) + cr;
        #pragma unroll
        for (int j = 0; j < 4; ++j) {
            const int col = (by << 7) + (wc << 6) + (j << 4) + cc;
            #pragma unroll
            for (int r = 0; r < 4; ++r)
                Cb[(size_t)(row + r) * N + col] = acc[i][j][r];
        }
    }
}

// ------------- masked row softmax, fp32 in -> bf16 linear out -------------
__global__ __launch_bounds__(256)
void softmax_mask_bf16(const float* __restrict__ attnF, unsigned short* __restrict__ attnB,
                       const unsigned char* __restrict__ maskg,
                       const int* __restrict__ maskMode, long rowOff)
{
    __shared__ float red[8];
    const long row = blockIdx.x;
    const float4* p = (const float4*)(attnF + row * (long)SS);
    float4 v = p[threadIdx.x];

    const long mrow = (rowOff + row) * (long)SS;
    if (*maskMode) {
        const uchar4 mk = ((const uchar4*)(maskg + mrow))[threadIdx.x];
        if (mk.x) v.x = -1000000.0f;
        if (mk.y) v.y = -1000000.0f;
        if (mk.z) v.z = -1000000.0f;
        if (mk.w) v.w = -1000000.0f;
    } else {
        const int4 mk = ((const int4*)((const int*)maskg + mrow))[threadIdx.x];
        if (mk.x) v.x = -1000000.0f;
        if (mk.y) v.y = -1000000.0f;
        if (mk.z) v.z = -1000000.0f;
        if (mk.w) v.w = -1000000.0f;
    }

    float m = fmaxf(fmaxf(v.x, v.y), fmaxf(v.z, v.w));
    #pragma unroll
    for (int off = 32; off; off >>= 1)
        m = fmaxf(m, __shfl_xor(m, off));
    const int wave = threadIdx.x >> 6;
    if ((threadIdx.x & 63) == 0) red[wave] = m;
    __syncthreads();
    m = fmaxf(fmaxf(red[0], red[1]), fmaxf(red[2], red[3]));

    v.x = __expf(v.x - m);
    v.y = __expf(v.y - m);
    v.z = __expf(v.z - m);
    v.w = __expf(v.w - m);

    float s = v.x + v.y + v.z + v.w;
    #pragma unroll
    for (int off = 32; off; off >>= 1)
        s += __shfl_xor(s, off);
    if ((threadIdx.x & 63) == 0) red[4 + wave] = s;
    __syncthreads();
    s = red[4] + red[5] + red[6] + red[7];

    const float inv = 1.0f / s;   // all-masked row -> uniform (matches ref)
    ushort4 o;
    o.x = f2bf(v.x * inv);
    o.y = f2bf(v.y * inv);
    o.z = f2bf(v.z * inv);
    o.w = f2bf(v.w * inv);
    *(ushort4*)(attnB + row * (long)SS + 4 * threadIdx.x) = o;
}

// ---------------- launcher ----------------
extern "C" void kernel_launch(void* const* d_in, const int* in_sizes, int n_in,
                              void* d_out, int out_size, void* d_ws, size_t ws_size,
                              hipStream_t stream)
{
    const float*         dec  = (const float*)d_in[0];          // [B,T,H]
    const float*         ctx  = (const float*)d_in[1];          // [B,S,2H]
    const unsigned char* mask = (const unsigned char*)d_in[2];  // [B,T,S]
    const float*         Wa   = (const float*)d_in[3];          // [H,2H]
    float* out = (float*)d_out;                                  // [B,T,2H]

    const size_t MBy = 1u << 20;
    const size_t perBatch = 12 * MBy;                 // A4 + B2 + C2 + D2 + E2
    const size_t fixed = 256 + 2 * MBy;               // flag + WaP(h,l)
    int G = (ws_size > fixed) ? (int)((ws_size - fixed) / perBatch) : 1;
    if (G > BB) G = BB;
    if (G < 1)  G = 1;

    char* p = (char*)d_ws;
    int* maskMode = (int*)p;                      p += 256;
    unsigned short* WaHP = (unsigned short*)p;    p += (size_t)HH * 2 * HH * 2;
    unsigned short* WaLP = (unsigned short*)p;    p += (size_t)HH * 2 * HH * 2;
    // region A (4MB/b): ctx packed hi+lo  |  attnF fp32
    unsigned short* ctxHP = (unsigned short*)p;
    unsigned short* ctxLP = ctxHP + (size_t)G * SS * 2 * HH;
    float*          attnF = (float*)p;            p += (size_t)G * 4 * MBy;
    // region B (2MB/b): dec packed hi+lo  |  attnB linear bf16
    unsigned short* decHP = (unsigned short*)p;
    unsigned short* decLP = decHP + (size_t)G * TT * HH;
    unsigned short* attnB = (unsigned short*)p;   p += (size_t)G * 2 * MBy;
    // region C (2MB/b): cin linear hi+lo  |  attnP packed
    unsigned short* cinH  = (unsigned short*)p;
    unsigned short* cinL  = cinH + (size_t)G * SS * HH;
    unsigned short* attnP = (unsigned short*)p;   p += (size_t)G * 2 * MBy;
    // region D (2MB/b): cin packed hi+lo
    unsigned short* cinHP = (unsigned short*)p;
    unsigned short* cinLP = cinHP + (size_t)G * SS * HH;  p += (size_t)G * 2 * MBy;
    // region E (2MB/b): ctxT packed
    unsigned short* ctxTP = (unsigned short*)p;   p += (size_t)G * 2 * MBy;

    detect_mask<<<1, 256, 0, stream>>>(mask, maskMode);
    // Wa [512 x 1024]: RT=4, KT=32
    split_pack<<<dim3(4 * 32, 1, 1), 256, 0, stream>>>(
        Wa, WaHP, WaLP, 2 * HH, 32, 0L, 0L);

    for (int g0 = 0; g0 < BB; g0 += G) {
        const int Gn = (BB - g0 < G) ? (BB - g0) : G;
        const float* ctxg = ctx + (size_t)g0 * SS * 2 * HH;

        // ctx [1024 x 1024]: RT=8, KT=32
        split_pack<<<dim3(8 * 32, 1, Gn), 256, 0, stream>>>(
            ctxg, ctxHP, ctxLP, 2 * HH, 32, (long)SS * 2 * HH, (long)SS * 2 * HH);
        // dec [1024 x 512]: RT=8, KT=16
        split_pack<<<dim3(8 * 16, 1, Gn), 256, 0, stream>>>(
            dec + (size_t)g0 * TT * HH, decHP, decLP, HH, 16,
            (long)TT * HH, (long)TT * HH);
        // ctxT packed from ctx
        transpose_pack<<<dim3(8, 32, Gn), 256, 0, stream>>>(
            ctxg, ctxTP, (long)SS * 2 * HH, (long)2 * HH * SS);

        // K1: cin = ctx . Wa^T  (M=S=1024, N=H=512, K=2H=1024, KTn=32)
        gemm2_x3<true><<<dim3(8, 4, Gn), 256, 0, stream>>>(
            ctxHP, ctxLP, WaHP, WaLP, nullptr, cinH, cinL,
            HH, 32, (long)SS * 2 * HH, 0L, (long)SS * HH);

        // pack cin [1024 x 512]: RT=8, KT=16
        pack_bf16<<<dim3(8 * 16, 1, Gn), 256, 0, stream>>>(
            cinH, cinHP, HH, 16, (long)SS * HH, (long)SS * HH);
        pack_bf16<<<dim3(8 * 16, 1, Gn), 256, 0, stream>>>(
            cinL, cinLP, HH, 16, (long)SS * HH, (long)SS * HH);

        // K2: attnF = dec . cin^T  (M=T=1024, N=S=1024, K=H=512, KTn=16)
        gemm2_x3<false><<<dim3(8, 8, Gn), 256, 0, stream>>>(
            decHP, decLP, cinHP, cinLP, attnF, nullptr, nullptr,
            SS, 16, (long)TT * HH, (long)SS * HH, (long)TT * SS);

        // K3: masked softmax -> attnB (linear bf16)
        softmax_mask_bf16<<<Gn * TT, 256, 0, stream>>>(
            attnF, attnB, mask, maskMode, (long)g0 * TT);

        // pack attn [1024 x 1024]: RT=8, KT=32
        pack_bf16<<<dim3(8 * 32, 1, Gn), 256, 0, stream>>>(
            attnB, attnP, SS, 32, (long)TT * SS, (long)TT * SS);

        // K4: out = attn . ctxT^T  (M=T=1024, N=2H=1024, K=S=1024, KTn=32)
        gemm2_x1<<<dim3(8, 8, Gn), 256, 0, stream>>>(
            attnP, ctxTP, out + (size_t)g0 * TT * 2 * HH,
            2 * HH, 32, (long)TT * SS, (long)2 * HH * SS, (long)TT * 2 * HH);
    }
}

// Round 11
// 415.520 us; speedup vs baseline: 2.3117x; 1.0442x over previous
//
#include <hip/hip_runtime.h>
#include <cstdint>
#include <cstddef>

// Luong attention. B=16, T=1024, S=1024, H=512
// Operands pre-PACKED in MFMA-fragment order (tile 128x32 = 8KB block;
// r = frag*16 + (lane&15), k = (lane>>4)*8 + e). Staging = contiguous
// 1KB/wave global_load_lds, zero bank conflicts (HW-verified r5/r8).
// GEMM K-loop: counted-vmcnt double buffer (T4): wait vmcnt(8) keeps the
// next tile's loads IN FLIGHT across the barrier; raw s_barrier (no drain);
// stage(kt+2) issued after compute. Never vmcnt(0) except final iteration.
//  K1: cin(h,l) = ctx . Wa^T    bf16x3, epilogue writes PACKED hi/lo
//  K2: attnF    = dec . cin^T   bf16x3
//  K3: masked softmax -> attnP  (writes PACKED bf16 directly)
//  K4: out      = attn . ctxT^T bf16x1
// ws per batch 12MB: A(4): ctxHP+LP | attnF ; B(2): decHP+LP ; C(2): attnP ;
//   D(2): cinHP+LP ; E(2): ctxTP.  +2MB WaP fixed.

constexpr int BB = 16;
constexpr int TT = 1024;
constexpr int SS = 1024;
constexpr int HH = 512;

typedef __attribute__((ext_vector_type(8))) short short8v;
typedef __attribute__((ext_vector_type(4))) float f32x4;

__device__ inline unsigned short f2bf(float x) {             // RNE fp32->bf16
    unsigned int u = __float_as_uint(x);
    return (unsigned short)((u + 0x7FFFu + ((u >> 16) & 1u)) >> 16);
}
__device__ inline float bf2f(unsigned short h) {
    return __uint_as_float(((unsigned int)h) << 16);
}
__device__ inline void gload16(const void* g, void* l) {
    __builtin_amdgcn_global_load_lds(
        (const __attribute__((address_space(1))) unsigned int*)g,
        (__attribute__((address_space(3))) unsigned int*)l, 16, 0, 0);
}

// ---------------- mask dtype detection (flag=1 byte-mask, 0 int32-mask) --------
__global__ __launch_bounds__(256)
void detect_mask(const unsigned char* __restrict__ mask, int* __restrict__ flag) {
    __shared__ int cnt;
    if (threadIdx.x == 0) cnt = 0;
    __syncthreads();
    int c = 0;
    for (int i = threadIdx.x; i < 4096; i += 256)
        if ((i & 3) != 0 && mask[i] != 0) c++;
    atomicAdd(&cnt, c);
    __syncthreads();
    if (threadIdx.x == 0) *flag = (cnt > 0) ? 1 : 0;
}

// -------- fp32 [R x K] -> packed bf16 hi & lo. grid.x = (R/128)*(K/32) --------
__global__ __launch_bounds__(256)
void split_pack(const float* __restrict__ in, unsigned short* __restrict__ oh,
                unsigned short* __restrict__ ol, int K, int KT, long sIn, long sOut)
{
    in += (size_t)blockIdx.z * sIn;
    oh += (size_t)blockIdx.z * sOut;
    ol += (size_t)blockIdx.z * sOut;
    const int rt = blockIdx.x / KT, kt = blockIdx.x % KT;
    const size_t tileBase = (size_t)blockIdx.x * 4096;
    #pragma unroll
    for (int s = 0; s < 2; ++s) {
        const int u  = threadIdx.x + (s << 8);
        const int r  = ((u >> 6) << 4) + (u & 15);
        const int k8 = ((u >> 4) & 3) << 3;
        const float* src = in + (size_t)(rt * 128 + r) * K + kt * 32 + k8;
        const float4 x = *(const float4*)src;
        const float4 y = *(const float4*)(src + 4);
        const float v[8] = {x.x, x.y, x.z, x.w, y.x, y.y, y.z, y.w};
        short8v H, L;
        #pragma unroll
        for (int j = 0; j < 8; ++j) {
            const unsigned short h = f2bf(v[j]);
            H[j] = (short)h;
            L[j] = (short)f2bf(v[j] - bf2f(h));
        }
        *(short8v*)(oh + tileBase + (size_t)u * 8) = H;
        *(short8v*)(ol + tileBase + (size_t)u * 8) = L;
    }
}

// -------- ctx [S x 2H] fp32 -> ctxT packed (rows=c, k=s), hi only --------
__global__ __launch_bounds__(256)
void transpose_pack(const float* __restrict__ src, unsigned short* __restrict__ dst,
                    long sIn, long sOut)
{
    __shared__ float t[32][132];
    src += (size_t)blockIdx.z * sIn;
    dst += (size_t)blockIdx.z * sOut;
    const int c0 = blockIdx.x << 7, s0 = blockIdx.y << 5;
    #pragma unroll
    for (int i = 0; i < 4; ++i) {
        const int fl = threadIdx.x + (i << 8);       // float4 id in 32x128 tile
        const int srow = fl >> 5, c4 = fl & 31;
        const float4 v = *(const float4*)(src + (size_t)(s0 + srow) * (2 * HH) + c0 + (c4 << 2));
        t[srow][(c4 << 2) + 0] = v.x;
        t[srow][(c4 << 2) + 1] = v.y;
        t[srow][(c4 << 2) + 2] = v.z;
        t[srow][(c4 << 2) + 3] = v.w;
    }
    __syncthreads();
    const size_t tileBase = ((size_t)blockIdx.x * (SS / 32) + blockIdx.y) * 4096;
    #pragma unroll
    for (int s = 0; s < 2; ++s) {
        const int u = threadIdx.x + (s << 8);
        const int r = ((u >> 6) << 4) + (u & 15);    // c-row within tile
        const int o = (u >> 4) & 3;                  // s-octet
        short8v H;
        #pragma unroll
        for (int e = 0; e < 8; ++e)
            H[e] = (short)f2bf(t[(o << 3) + e][r]);
        *(short8v*)(dst + tileBase + (size_t)u * 8) = H;
    }
}

// -------- bf16x3 GEMM, packed operands, counted-vmcnt double buffer --------
// C[M,N] = sum (Ah+Al)[m,k]*(Bh+Bl)[n,k]; 128x128 tile, BK=32, 4 waves.
// SPLIT: epilogue writes C as PACKED bf16 hi/lo (KT = N/32); else fp32 linear.
template <bool SPLIT>
__global__ __launch_bounds__(256, 2)
void gemm2_x3(const unsigned short* __restrict__ Ah, const unsigned short* __restrict__ Al,
              const unsigned short* __restrict__ Bh, const unsigned short* __restrict__ Bl,
              float* __restrict__ C, unsigned short* __restrict__ CH,
              unsigned short* __restrict__ CL,
              int N, int KTn, long sA, long sB, long sC)
{
    const int bz = blockIdx.z;
    const int tid = threadIdx.x, lane = tid & 63, wv = tid >> 6;
    const int wr = wv >> 1, wc = wv & 1;
    const int bx = blockIdx.x, by = blockIdx.y;

    __shared__ short sm[2][4][4096];    // [buf][Ah,Al,Bh,Bl][frag*512+lane*8]

    const unsigned short* base =
        (wv == 0) ? Ah + (size_t)bz * sA : (wv == 1) ? Al + (size_t)bz * sA
      : (wv == 2) ? Bh + (size_t)bz * sB :            Bl + (size_t)bz * sB;
    const unsigned short* gsrc = base
        + (size_t)((wv < 2) ? bx : by) * KTn * 4096 + (size_t)lane * 8;

    f32x4 acc[4][4];
    #pragma unroll
    for (int i = 0; i < 4; ++i)
        #pragma unroll
        for (int j = 0; j < 4; ++j)
            acc[i][j] = (f32x4)(0.0f);

    // prologue: stage tiles 0 and 1
    #pragma unroll
    for (int f = 0; f < 8; ++f)
        gload16(gsrc + f * 512, &sm[0][wv][f * 512]);
    #pragma unroll
    for (int f = 0; f < 8; ++f)
        gload16(gsrc + 4096 + f * 512, &sm[1][wv][f * 512]);

    for (int kt = 0; kt < KTn; ++kt) {
        // stage(kt) complete; stage(kt+1) stays in flight across the barrier
        if (kt + 1 < KTn) asm volatile("s_waitcnt vmcnt(8)" ::: "memory");
        else              asm volatile("s_waitcnt vmcnt(0)" ::: "memory");
        __builtin_amdgcn_s_barrier();
        __builtin_amdgcn_sched_barrier(0);
        const int cur = kt & 1;

        short8v ah[4], al[4], bh[4], bl[4];
        #pragma unroll
        for (int f = 0; f < 4; ++f) {
            const int fa = (((wr << 2) + f) * 64 + lane) * 8;
            const int fb = (((wc << 2) + f) * 64 + lane) * 8;
            ah[f] = *(const short8v*)&sm[cur][0][fa];
            al[f] = *(const short8v*)&sm[cur][1][fa];
            bh[f] = *(const short8v*)&sm[cur][2][fb];
            bl[f] = *(const short8v*)&sm[cur][3][fb];
        }
        #pragma unroll
        for (int i = 0; i < 4; ++i)
            #pragma unroll
            for (int j = 0; j < 4; ++j) {
                acc[i][j] = __builtin_amdgcn_mfma_f32_16x16x32_bf16(ah[i], bh[j], acc[i][j], 0, 0, 0);
                acc[i][j] = __builtin_amdgcn_mfma_f32_16x16x32_bf16(ah[i], bl[j], acc[i][j], 0, 0, 0);
                acc[i][j] = __builtin_amdgcn_mfma_f32_16x16x32_bf16(al[i], bh[j], acc[i][j], 0, 0, 0);
            }

        __builtin_amdgcn_s_barrier();   // all waves' reads of sm[cur] done
        __builtin_amdgcn_sched_barrier(0);
        if (kt + 2 < KTn) {             // refill just-consumed buffer
            const unsigned short* g = gsrc + (size_t)(kt + 2) * 4096;
            #pragma unroll
            for (int f = 0; f < 8; ++f)
                gload16(g + f * 512, &sm[cur][wv][f * 512]);
        }
    }

    // C/D: col = lane&15, row = (lane>>4)*4 + reg  (HW-verified)
    const int cr = (lane >> 4) << 2, cc = lane & 15;
    if (SPLIT) {
        const int KTt = N >> 5;         // packed output: KT tiles of 32 cols
        #pragma unroll
        for (int i = 0; i < 4; ++i) {
            const int frag = (wr << 2) + i;
            #pragma unroll
            for (int j = 0; j < 4; ++j) {
                const int kt  = (by << 2) + (wc << 1) + (j >> 1);
                const int oct = ((j & 1) << 1) + (cc >> 3);
                const int e   = cc & 7;
                #pragma unroll
                for (int r = 0; r < 4; ++r) {
                    const int l16 = cr + r;
                    const size_t idx = (size_t)bz * sC
                        + ((size_t)(bx * KTt + kt) << 12)
                        + (size_t)(((frag << 6) + (oct << 4) + l16) << 3) + e;
                    const float v = acc[i][j][r];
                    const unsigned short h = f2bf(v);
                    CH[idx] = h;
                    CL[idx] = f2bf(v - bf2f(h));
                }
            }
        }
    } else {
        #pragma unroll
        for (int i = 0; i < 4; ++i) {
            const int row = (bx << 7) + (wr << 6) + (i << 4) + cr;
            #pragma unroll
            for (int j = 0; j < 4; ++j) {
                const int col = (by << 7) + (wc << 6) + (j << 4) + cc;
                #pragma unroll
                for (int r = 0; r < 4; ++r)
                    C[(size_t)bz * sC + (size_t)(row + r) * N + col] = acc[i][j][r];
            }
        }
    }
}

// -------- bf16x1 GEMM, packed operands, counted-vmcnt double buffer --------
__global__ __launch_bounds__(256, 2)
void gemm2_x1(const unsigned short* __restrict__ A, const unsigned short* __restrict__ B,
              float* __restrict__ C, int N, int KTn, long sA, long sB, long sC)
{
    const int bz = blockIdx.z;
    const int tid = threadIdx.x, lane = tid & 63, wv = tid >> 6;
    const int wr = wv >> 1, wc = wv & 1;
    const int bx = blockIdx.x, by = blockIdx.y;

    __shared__ short sm[2][2][4096];    // [buf][A,B][...]

    const int half = wv & 1;
    const unsigned short* base = (wv < 2) ? A + (size_t)bz * sA : B + (size_t)bz * sB;
    const unsigned short* gsrc = base
        + (size_t)((wv < 2) ? bx : by) * KTn * 4096 + (size_t)(half * 4) * 512
        + (size_t)lane * 8;
    const int arr = (wv < 2) ? 0 : 1;

    f32x4 acc[4][4];
    #pragma unroll
    for (int i = 0; i < 4; ++i)
        #pragma unroll
        for (int j = 0; j < 4; ++j)
            acc[i][j] = (f32x4)(0.0f);

    #pragma unroll
    for (int f = 0; f < 4; ++f)
        gload16(gsrc + f * 512, &sm[0][arr][half * 2048 + f * 512]);
    #pragma unroll
    for (int f = 0; f < 4; ++f)
        gload16(gsrc + 4096 + f * 512, &sm[1][arr][half * 2048 + f * 512]);

    for (int kt = 0; kt < KTn; ++kt) {
        if (kt + 1 < KTn) asm volatile("s_waitcnt vmcnt(4)" ::: "memory");
        else              asm volatile("s_waitcnt vmcnt(0)" ::: "memory");
        __builtin_amdgcn_s_barrier();
        __builtin_amdgcn_sched_barrier(0);
        const int cur = kt & 1;

        short8v a[4], b[4];
        #pragma unroll
        for (int f = 0; f < 4; ++f) {
            a[f] = *(const short8v*)&sm[cur][0][(((wr << 2) + f) * 64 + lane) * 8];
            b[f] = *(const short8v*)&sm[cur][1][(((wc << 2) + f) * 64 + lane) * 8];
        }
        #pragma unroll
        for (int i = 0; i < 4; ++i)
            #pragma unroll
            for (int j = 0; j < 4; ++j)
                acc[i][j] = __builtin_amdgcn_mfma_f32_16x16x32_bf16(a[i], b[j], acc[i][j], 0, 0, 0);

        __builtin_amdgcn_s_barrier();
        __builtin_amdgcn_sched_barrier(0);
        if (kt + 2 < KTn) {
            const unsigned short* g = gsrc + (size_t)(kt + 2) * 4096;
            #pragma unroll
            for (int f = 0; f < 4; ++f)
                gload16(g + f * 512, &sm[cur][arr][half * 2048 + f * 512]);
        }
    }

    float* Cb = C + (size_t)bz * sC;
    const int cr = (lane >> 4) << 2, cc = lane & 15;
    #pragma unroll
    for (int i = 0; i < 4; ++i) {
        const int row = (bx << 7) + (wr << 6) + (i << 4) + cr;
        #pragma unroll
        for (int j = 0; j < 4; ++j) {
            const int col = (by << 7) + (wc << 6) + (j << 4) + cc;
            #pragma unroll
            for (int r = 0; r < 4; ++r)
                Cb[(size_t)(row + r) * N + col] = acc[i][j][r];
        }
    }
}

// ------- masked row softmax, fp32 in -> PACKED bf16 out, 1 block/row -------
__global__ __launch_bounds__(256)
void softmax_mask_pack(const float* __restrict__ attnF, unsigned short* __restrict__ attnP,
                       const unsigned char* __restrict__ maskg,
                       const int* __restrict__ maskMode, long rowOff)
{
    __shared__ float red[8];
    const long row = blockIdx.x;
    const float4* p = (const float4*)(attnF + row * (long)SS);
    float4 v = p[threadIdx.x];

    const long mrow = (rowOff + row) * (long)SS;
    if (*maskMode) {
        const uchar4 mk = ((const uchar4*)(maskg + mrow))[threadIdx.x];
        if (mk.x) v.x = -1000000.0f;
        if (mk.y) v.y = -1000000.0f;
        if (mk.z) v.z = -1000000.0f;
        if (mk.w) v.w = -1000000.0f;
    } else {
        const int4 mk = ((const int4*)((const int*)maskg + mrow))[threadIdx.x];
        if (mk.x) v.x = -1000000.0f;
        if (mk.y) v.y = -1000000.0f;
        if (mk.z) v.z = -1000000.0f;
        if (mk.w) v.w = -1000000.0f;
    }

    float m = fmaxf(fmaxf(v.x, v.y), fmaxf(v.z, v.w));
    #pragma unroll
    for (int off = 32; off; off >>= 1)
        m = fmaxf(m, __shfl_xor(m, off));
    const int wave = threadIdx.x >> 6;
    if ((threadIdx.x & 63) == 0) red[wave] = m;
    __syncthreads();
    m = fmaxf(fmaxf(red[0], red[1]), fmaxf(red[2], red[3]));

    v.x = __expf(v.x - m);
    v.y = __expf(v.y - m);
    v.z = __expf(v.z - m);
    v.w = __expf(v.w - m);

    float s = v.x + v.y + v.z + v.w;
    #pragma unroll
    for (int off = 32; off; off >>= 1)
        s += __shfl_xor(s, off);
    if ((threadIdx.x & 63) == 0) red[4 + wave] = s;
    __syncthreads();
    s = red[4] + red[5] + red[6] + red[7];

    const float inv = 1.0f / s;   // all-masked row -> uniform (matches ref)
    ushort4 o;
    o.x = f2bf(v.x * inv);
    o.y = f2bf(v.y * inv);
    o.z = f2bf(v.z * inv);
    o.w = f2bf(v.w * inv);

    // packed write: attn [T x S], KT=32. t = row&1023, batch g = row>>10.
    const int t = (int)(row & (TT - 1));
    const int g = (int)(row >> 10);
    const int s0 = threadIdx.x << 2;
    const int rt = t >> 7, frag = (t >> 4) & 7, l16 = t & 15;
    const int kt = s0 >> 5, oct = (s0 >> 3) & 3, e0 = s0 & 7;   // e0 in {0,4}
    const size_t idx = (size_t)g * TT * SS
        + ((size_t)(rt * 32 + kt) << 12)
        + (size_t)(((frag << 6) + (oct << 4) + l16) << 3) + e0;
    *(ushort4*)(attnP + idx) = o;
}

// ---------------- launcher ----------------
extern "C" void kernel_launch(void* const* d_in, const int* in_sizes, int n_in,
                              void* d_out, int out_size, void* d_ws, size_t ws_size,
                              hipStream_t stream)
{
    const float*         dec  = (const float*)d_in[0];          // [B,T,H]
    const float*         ctx  = (const float*)d_in[1];          // [B,S,2H]
    const unsigned char* mask = (const unsigned char*)d_in[2];  // [B,T,S]
    const float*         Wa   = (const float*)d_in[3];          // [H,2H]
    float* out = (float*)d_out;                                  // [B,T,2H]

    const size_t MBy = 1u << 20;
    const size_t perBatch = 12 * MBy;                 // A4 + B2 + C2 + D2 + E2
    const size_t fixed = 256 + 2 * MBy;               // flag + WaP(h,l)
    int G = (ws_size > fixed) ? (int)((ws_size - fixed) / perBatch) : 1;
    if (G > BB) G = BB;
    if (G < 1)  G = 1;

    char* p = (char*)d_ws;
    int* maskMode = (int*)p;                      p += 256;
    unsigned short* WaHP = (unsigned short*)p;    p += (size_t)HH * 2 * HH * 2;
    unsigned short* WaLP = (unsigned short*)p;    p += (size_t)HH * 2 * HH * 2;
    // region A (4MB/b): ctx packed hi+lo  |  attnF fp32
    unsigned short* ctxHP = (unsigned short*)p;
    unsigned short* ctxLP = ctxHP + (size_t)G * SS * 2 * HH;
    float*          attnF = (float*)p;            p += (size_t)G * 4 * MBy;
    // region B (2MB/b): dec packed hi+lo
    unsigned short* decHP = (unsigned short*)p;
    unsigned short* decLP = decHP + (size_t)G * TT * HH;
    p += (size_t)G * 2 * MBy;
    // region C (2MB/b): attn packed
    unsigned short* attnP = (unsigned short*)p;   p += (size_t)G * 2 * MBy;
    // region D (2MB/b): cin packed hi+lo (written directly by K1)
    unsigned short* cinHP = (unsigned short*)p;
    unsigned short* cinLP = cinHP + (size_t)G * SS * HH;  p += (size_t)G * 2 * MBy;
    // region E (2MB/b): ctxT packed
    unsigned short* ctxTP = (unsigned short*)p;   p += (size_t)G * 2 * MBy;

    detect_mask<<<1, 256, 0, stream>>>(mask, maskMode);
    // Wa [512 x 1024]: RT=4, KT=32
    split_pack<<<dim3(4 * 32, 1, 1), 256, 0, stream>>>(
        Wa, WaHP, WaLP, 2 * HH, 32, 0L, 0L);

    for (int g0 = 0; g0 < BB; g0 += G) {
        const int Gn = (BB - g0 < G) ? (BB - g0) : G;
        const float* ctxg = ctx + (size_t)g0 * SS * 2 * HH;

        // ctx [1024 x 1024]: RT=8, KT=32
        split_pack<<<dim3(8 * 32, 1, Gn), 256, 0, stream>>>(
            ctxg, ctxHP, ctxLP, 2 * HH, 32, (long)SS * 2 * HH, (long)SS * 2 * HH);
        // dec [1024 x 512]: RT=8, KT=16
        split_pack<<<dim3(8 * 16, 1, Gn), 256, 0, stream>>>(
            dec + (size_t)g0 * TT * HH, decHP, decLP, HH, 16,
            (long)TT * HH, (long)TT * HH);
        // ctxT packed from ctx
        transpose_pack<<<dim3(8, 32, Gn), 256, 0, stream>>>(
            ctxg, ctxTP, (long)SS * 2 * HH, (long)2 * HH * SS);

        // K1: cin = ctx . Wa^T  (M=S=1024, N=H=512, KTn=32) -> PACKED hi/lo
        gemm2_x3<true><<<dim3(8, 4, Gn), 256, 0, stream>>>(
            ctxHP, ctxLP, WaHP, WaLP, nullptr, cinHP, cinLP,
            HH, 32, (long)SS * 2 * HH, 0L, (long)SS * HH);

        // K2: attnF = dec . cin^T  (M=T=1024, N=S=1024, KTn=16)
        gemm2_x3<false><<<dim3(8, 8, Gn), 256, 0, stream>>>(
            decHP, decLP, cinHP, cinLP, attnF, nullptr, nullptr,
            SS, 16, (long)TT * HH, (long)SS * HH, (long)TT * SS);

        // K3: masked softmax -> attnP (packed bf16)
        softmax_mask_pack<<<Gn * TT, 256, 0, stream>>>(
            attnF, attnP, mask, maskMode, (long)g0 * TT);

        // K4: out = attn . ctxT^T  (M=T=1024, N=2H=1024, KTn=32)
        gemm2_x1<<<dim3(8, 8, Gn), 256, 0, stream>>>(
            attnP, ctxTP, out + (size_t)g0 * TT * 2 * HH,
            2 * HH, 32, (long)TT * SS, (long)2 * HH * SS, (long)TT * 2 * HH);
    }
}